// Round 11
// baseline (19.252 us; speedup 1.0000x reference)
//
#include <hip/hip_runtime.h>

// SeparableWeightedConv R10: R9 structure with CH=4 (2048 blocks).
// Theory: latency-bound at 16 waves/CU; halving per-block channel work
// doubles block count -> ~24 waves/CU. Prologue is now cheap (shuffle coords
// + fast sqrt), so duplication cost (+33% instr) < TLP gain if theory holds.

#define BB 8
#define CC 128
#define NN 8192
#define KK 9

constexpr int CH      = 4;            // channels per block
constexpr int CGROUPS = CC / CH;      // 32
constexpr int LTILE   = 1024;         // 256 thr x 4 l
constexpr int LTILES  = NN / LTILE;   // 8
constexpr int THREADS = 256;

typedef float vfloat4 __attribute__((ext_vector_type(4)));

struct Stage { float4 M, L, R; };     // L/R only meaningful on lanes 0/63

__global__ __launch_bounds__(THREADS)
void sepwconv_kernel(const float* __restrict__ x,
                     const float* __restrict__ coords,
                     const float* __restrict__ sigma,
                     const float* __restrict__ weight,
                     float* __restrict__ out)
{
    const int bid = blockIdx.x;
    const int cg  = bid % CGROUPS;
    const int lt  = (bid / CGROUPS) % LTILES;
    const int b   = bid / (CGROUPS * LTILES);
    const int t   = threadIdx.x;
    const int lane = t & 63;
    const int l0  = lt * LTILE + t * 4;

    const float inv_sigma = 1.0f / sigma[0];

    const float* cx = coords + (size_t)(b * 3 + 0) * NN;
    const float* cy = coords + (size_t)(b * 3 + 1) * NN;
    const float* cz = coords + (size_t)(b * 3 + 2) * NN;

    // --- coord center quads (always in-bounds) ---
    float4 cxm = *(const float4*)(cx + l0);
    float4 cym = *(const float4*)(cy + l0);
    float4 czm = *(const float4*)(cz + l0);

    // edge-lane halo loads; OOB -> 0 (x==0 kills those taps)
    float4 cxL = {0,0,0,0}, cyL = {0,0,0,0}, czL = {0,0,0,0};
    float4 cxR = {0,0,0,0}, cyR = {0,0,0,0}, czR = {0,0,0,0};
    if (lane == 0 && l0 >= 4) {
        cxL = *(const float4*)(cx + l0 - 4);
        cyL = *(const float4*)(cy + l0 - 4);
        czL = *(const float4*)(cz + l0 - 4);
    }
    if (lane == 63 && l0 + 8 <= NN) {
        cxR = *(const float4*)(cx + l0 + 4);
        cyR = *(const float4*)(cy + l0 + 4);
        czR = *(const float4*)(cz + l0 + 4);
    }

    const float* xbase = x + ((size_t)b * CC + cg * CH) * NN;

    // x stage loader: center quad always; halo quads only on edge lanes
    auto loadStage = [&](int i) -> Stage {
        Stage s;
        const float* xp = xbase + (size_t)i * NN;
        s.M = *(const float4*)(xp + l0);
        s.L = make_float4(0.f, 0.f, 0.f, 0.f);
        s.R = make_float4(0.f, 0.f, 0.f, 0.f);
        if (lane == 0 && l0 >= 4)        s.L = *(const float4*)(xp + l0 - 4);
        if (lane == 63 && l0 + 8 <= NN)  s.R = *(const float4*)(xp + l0 + 4);
        return s;
    };

    // issue ch0+ch1 x stages before the dw chain (2 loads in flight)
    Stage S0 = loadStage(0);
    Stage S1 = loadStage(1);

    // --- build 12-wide coord windows via wave shuffles ---
    auto haloWindow = [&](const float4& M, const float4& L, const float4& R, float* v) {
        v[4] = M.x; v[5] = M.y; v[6] = M.z; v[7] = M.w;
        v[0] = __shfl_up(M.x, 1);
        v[1] = __shfl_up(M.y, 1);
        v[2] = __shfl_up(M.z, 1);
        v[3] = __shfl_up(M.w, 1);
        v[8]  = __shfl_down(M.x, 1);
        v[9]  = __shfl_down(M.y, 1);
        v[10] = __shfl_down(M.z, 1);
        v[11] = __shfl_down(M.w, 1);
        if (lane == 0)  { v[0] = L.x; v[1] = L.y; v[2] = L.z; v[3] = L.w; }
        if (lane == 63) { v[8] = R.x; v[9] = R.y; v[10] = R.z; v[11] = R.w; }
    };

    float cxv[12], cyv[12], czv[12];
    haloWindow(cxm, cxL, cxR, cxv);
    haloWindow(cym, cyL, cyR, cyv);
    haloWindow(czm, czL, czR, czv);

    // --- dw[jl][k]: distance weights, shared across channels ---
    float dw[4][KK];
    #pragma unroll
    for (int jl = 0; jl < 4; ++jl) {
        const float ccx = cxv[jl + 4], ccy = cyv[jl + 4], ccz = czv[jl + 4];
        #pragma unroll
        for (int k = 0; k < KK; ++k) {
            const float dx = cxv[jl + k] - ccx;
            const float dy = cyv[jl + k] - ccy;
            const float dz = czv[jl + k] - ccz;
            const float sq = fmaf(dx, dx, fmaf(dy, dy, dz * dz));
            const float dist = __builtin_amdgcn_sqrtf(sq);   // v_sqrt_f32; sqrt(0)==0
            dw[jl][k] = fmaxf(fmaf(-inv_sigma, dist, 1.0f), 0.0f);
        }
    }

    // --- compute one channel from its stage ---
    auto compute = [&](int i, const Stage& s) {
        float lx0 = __shfl_up(s.M.x, 1);
        float lx1 = __shfl_up(s.M.y, 1);
        float lx2 = __shfl_up(s.M.z, 1);
        float lx3 = __shfl_up(s.M.w, 1);
        float rx0 = __shfl_down(s.M.x, 1);
        float rx1 = __shfl_down(s.M.y, 1);
        float rx2 = __shfl_down(s.M.z, 1);
        float rx3 = __shfl_down(s.M.w, 1);
        if (lane == 0)  { lx0 = s.L.x; lx1 = s.L.y; lx2 = s.L.z; lx3 = s.L.w; }
        if (lane == 63) { rx0 = s.R.x; rx1 = s.R.y; rx2 = s.R.z; rx3 = s.R.w; }

        const float* wr = weight + (size_t)(cg * CH + i) * KK;  // wave-uniform
        float w[KK];
        #pragma unroll
        for (int k = 0; k < KK; ++k) w[k] = wr[k];

        const float xv[12] = {lx0, lx1, lx2, lx3,
                              s.M.x, s.M.y, s.M.z, s.M.w,
                              rx0, rx1, rx2, rx3};
        float acc[4] = {0.f, 0.f, 0.f, 0.f};
        #pragma unroll
        for (int jl = 0; jl < 4; ++jl)
            #pragma unroll
            for (int k = 0; k < KK; ++k)
                acc[jl] = fmaf(xv[jl + k] * dw[jl][k], w[k], acc[jl]);

        vfloat4 o = {acc[0], acc[1], acc[2], acc[3]};
        __builtin_nontemporal_store(o, (vfloat4*)(out + ((size_t)b * CC + cg * CH + i) * NN + l0));
    };

    // --- pipelined channel sequence (4 channels, 2 stages pre-issued) ---
    Stage S2 = loadStage(2); compute(0, S0);
    S0 = loadStage(3);       compute(1, S1);
    compute(2, S2);
    compute(3, S0);
}

extern "C" void kernel_launch(void* const* d_in, const int* in_sizes, int n_in,
                              void* d_out, int out_size, void* d_ws, size_t ws_size,
                              hipStream_t stream) {
    const float* x      = (const float*)d_in[0];
    const float* coords = (const float*)d_in[1];
    const float* sigma  = (const float*)d_in[2];
    const float* weight = (const float*)d_in[3];
    float* out = (float*)d_out;

    dim3 grid(BB * LTILES * CGROUPS);   // 8 * 8 * 32 = 2048 blocks
    sepwconv_kernel<<<grid, THREADS, 0, stream>>>(x, coords, sigma, weight, out);
}

// Round 12
// 16.204 us; speedup vs baseline: 1.1881x; 1.1881x over previous
//
#include <hip/hip_runtime.h>

// SeparableWeightedConv R11: CH=8 champion + (1) depth-4 rolling load
// pipeline (4 byte-light stages in flight before the dw chain; every compute
// covered by >=3 computes of issue), (2) combined single-instruction halo
// load (lane0 left / lane63 right share one predicated vmem op, per-lane addr).

#define BB 8
#define CC 128
#define NN 8192
#define KK 9

constexpr int CH      = 8;            // channels per block
constexpr int CGROUPS = CC / CH;      // 16
constexpr int LTILE   = 1024;         // 256 thr x 4 l
constexpr int LTILES  = NN / LTILE;   // 8
constexpr int THREADS = 256;

typedef float vfloat4 __attribute__((ext_vector_type(4)));

__global__ __launch_bounds__(THREADS)
void sepwconv_kernel(const float* __restrict__ x,
                     const float* __restrict__ coords,
                     const float* __restrict__ sigma,
                     const float* __restrict__ weight,
                     float* __restrict__ out)
{
    const int bid = blockIdx.x;
    const int cg  = bid % CGROUPS;
    const int lt  = (bid / CGROUPS) % LTILES;
    const int b   = bid / (CGROUPS * LTILES);
    const int t   = threadIdx.x;
    const int lane = t & 63;
    const int l0  = lt * LTILE + t * 4;

    const float inv_sigma = 1.0f / sigma[0];

    // edge predicates: lane0 needs left halo quad, lane63 needs right halo quad
    const bool ledge = (lane == 0)  && (l0 >= 4);
    const bool redge = (lane == 63) && (l0 + 8 <= NN);
    const bool edge  = ledge || redge;
    const int  hoff  = (lane == 0) ? -4 : 4;   // per-lane halo offset

    const float* cx = coords + (size_t)(b * 3 + 0) * NN;
    const float* cy = coords + (size_t)(b * 3 + 1) * NN;
    const float* cz = coords + (size_t)(b * 3 + 2) * NN;

    // --- coord center quads + combined halo loads (one vmem op per dim) ---
    float4 cxm = *(const float4*)(cx + l0);
    float4 cym = *(const float4*)(cy + l0);
    float4 czm = *(const float4*)(cz + l0);
    float4 cxH = {0,0,0,0}, cyH = {0,0,0,0}, czH = {0,0,0,0};
    if (edge) {
        cxH = *(const float4*)(cx + l0 + hoff);
        cyH = *(const float4*)(cy + l0 + hoff);
        czH = *(const float4*)(cz + l0 + hoff);
    }

    const float* xbase = x + ((size_t)b * CC + cg * CH) * NN;

    auto loadM = [&](int i) -> float4 {
        return *(const float4*)(xbase + (size_t)i * NN + l0);
    };
    auto loadH = [&](int i) -> float4 {
        float4 h = {0.f, 0.f, 0.f, 0.f};
        if (edge) h = *(const float4*)(xbase + (size_t)i * NN + l0 + hoff);
        return h;
    };

    // --- issue 4 stages before the dw chain (depth-4 pipeline) ---
    float4 M0 = loadM(0), H0 = loadH(0);
    float4 M1 = loadM(1), H1 = loadH(1);
    float4 M2 = loadM(2), H2 = loadH(2);
    float4 M3 = loadM(3), H3 = loadH(3);

    // --- build 12-wide coord windows via wave shuffles ---
    auto haloWindow = [&](const float4& M, const float4& H, float* v) {
        v[4] = M.x; v[5] = M.y; v[6] = M.z; v[7] = M.w;
        v[0] = __shfl_up(M.x, 1);
        v[1] = __shfl_up(M.y, 1);
        v[2] = __shfl_up(M.z, 1);
        v[3] = __shfl_up(M.w, 1);
        v[8]  = __shfl_down(M.x, 1);
        v[9]  = __shfl_down(M.y, 1);
        v[10] = __shfl_down(M.z, 1);
        v[11] = __shfl_down(M.w, 1);
        if (lane == 0)  { v[0] = H.x; v[1] = H.y; v[2] = H.z; v[3] = H.w; }
        if (lane == 63) { v[8] = H.x; v[9] = H.y; v[10] = H.z; v[11] = H.w; }
    };

    float cxv[12], cyv[12], czv[12];
    haloWindow(cxm, cxH, cxv);
    haloWindow(cym, cyH, cyv);
    haloWindow(czm, czH, czv);

    // --- dw[jl][k]: distance weights, shared across channels ---
    float dw[4][KK];
    #pragma unroll
    for (int jl = 0; jl < 4; ++jl) {
        const float ccx = cxv[jl + 4], ccy = cyv[jl + 4], ccz = czv[jl + 4];
        #pragma unroll
        for (int k = 0; k < KK; ++k) {
            const float dx = cxv[jl + k] - ccx;
            const float dy = cyv[jl + k] - ccy;
            const float dz = czv[jl + k] - ccz;
            const float sq = fmaf(dx, dx, fmaf(dy, dy, dz * dz));
            const float dist = __builtin_amdgcn_sqrtf(sq);   // v_sqrt_f32; sqrt(0)==0
            dw[jl][k] = fmaxf(fmaf(-inv_sigma, dist, 1.0f), 0.0f);
        }
    }

    // --- compute one channel from its stage (M + combined halo H) ---
    auto compute = [&](int i, const float4& M, const float4& H) {
        float lx0 = __shfl_up(M.x, 1);
        float lx1 = __shfl_up(M.y, 1);
        float lx2 = __shfl_up(M.z, 1);
        float lx3 = __shfl_up(M.w, 1);
        float rx0 = __shfl_down(M.x, 1);
        float rx1 = __shfl_down(M.y, 1);
        float rx2 = __shfl_down(M.z, 1);
        float rx3 = __shfl_down(M.w, 1);
        if (lane == 0)  { lx0 = H.x; lx1 = H.y; lx2 = H.z; lx3 = H.w; }
        if (lane == 63) { rx0 = H.x; rx1 = H.y; rx2 = H.z; rx3 = H.w; }

        const float* wr = weight + (size_t)(cg * CH + i) * KK;  // wave-uniform
        float w[KK];
        #pragma unroll
        for (int k = 0; k < KK; ++k) w[k] = wr[k];

        const float xv[12] = {lx0, lx1, lx2, lx3,
                              M.x, M.y, M.z, M.w,
                              rx0, rx1, rx2, rx3};
        float acc[4] = {0.f, 0.f, 0.f, 0.f};
        #pragma unroll
        for (int jl = 0; jl < 4; ++jl)
            #pragma unroll
            for (int k = 0; k < KK; ++k)
                acc[jl] = fmaf(xv[jl + k] * dw[jl][k], w[k], acc[jl]);

        vfloat4 o = {acc[0], acc[1], acc[2], acc[3]};
        __builtin_nontemporal_store(o, (vfloat4*)(out + ((size_t)b * CC + cg * CH + i) * NN + l0));
    };

    // --- depth-4 rolling pipeline: compute i, issue stage i+4 ---
    compute(0, M0, H0); float4 M4 = loadM(4), H4 = loadH(4);
    compute(1, M1, H1); float4 M5 = loadM(5), H5 = loadH(5);
    compute(2, M2, H2); float4 M6 = loadM(6), H6 = loadH(6);
    compute(3, M3, H3); float4 M7 = loadM(7), H7 = loadH(7);
    compute(4, M4, H4);
    compute(5, M5, H5);
    compute(6, M6, H6);
    compute(7, M7, H7);
}

extern "C" void kernel_launch(void* const* d_in, const int* in_sizes, int n_in,
                              void* d_out, int out_size, void* d_ws, size_t ws_size,
                              hipStream_t stream) {
    const float* x      = (const float*)d_in[0];
    const float* coords = (const float*)d_in[1];
    const float* sigma  = (const float*)d_in[2];
    const float* weight = (const float*)d_in[3];
    float* out = (float*)d_out;

    dim3 grid(BB * LTILES * CGROUPS);   // 1024 blocks
    sepwconv_kernel<<<grid, THREADS, 0, stream>>>(x, coords, sigma, weight, out);
}